// Round 1
// baseline (334.543 us; speedup 1.0000x reference)
//
#include <hip/hip_runtime.h>
#include <math.h>

constexpr int DIM = 64;
constexpr int S = 8;
constexpr int WPB = 4;                 // waves per block
constexpr int BLOCK = WPB * 64;

__global__ __launch_bounds__(BLOCK)
void sestkgcn_kernel(
    const int*   __restrict__ u_idx,
    const int*   __restrict__ v_idx,
    const float* __restrict__ usr_feat,
    const float* __restrict__ item_feat,
    const float* __restrict__ rel_feat,
    const int*   __restrict__ neigh_uu,
    const float* __restrict__ neigh_uu_st,
    const int*   __restrict__ neigh_ui,
    const float* __restrict__ neigh_ui_rat,
    const float* __restrict__ neigh_ui_vot,
    const float* __restrict__ neigh_ui_tim,
    const int*   __restrict__ neigh_iu,
    const float* __restrict__ neigh_iu_rat,
    const float* __restrict__ neigh_iu_vot,
    const float* __restrict__ neigh_iu_tim,
    const int*   __restrict__ neigh_ii,
    const int*   __restrict__ neigh_ir,
    const float* __restrict__ Wu,
    const float* __restrict__ bu,
    const float* __restrict__ Wv,
    const float* __restrict__ bv,
    float*       __restrict__ out,
    int n)
{
    __shared__ float sWu[DIM * DIM];
    __shared__ float sWv[DIM * DIM];
    __shared__ float sbu[DIM];
    __shared__ float sbv[DIM];

    const int tid = threadIdx.x;
    for (int i = tid; i < DIM * DIM; i += BLOCK) {
        sWu[i] = Wu[i];
        sWv[i] = Wv[i];
    }
    if (tid < DIM) { sbu[tid] = bu[tid]; sbv[tid] = bv[tid]; }
    __syncthreads();

    const int wave = tid >> 6;
    const int lane = tid & 63;
    const int b = blockIdx.x * WPB + wave;
    if (b >= n) return;

    const int u = u_idx[b];
    const int v = v_idx[b];

    const float u_d = usr_feat[(long)u * DIM + lane];
    const float v_d = item_feat[(long)v * DIM + lane];

    // ---------------- user side ----------------
    // social neighbors: softmax over tie strength
    float w[S];
    {
        float m = -INFINITY;
        #pragma unroll
        for (int s = 0; s < S; s++) { w[s] = neigh_uu_st[(long)u * S + s]; m = fmaxf(m, w[s]); }
        float sum = 0.f;
        #pragma unroll
        for (int s = 0; s < S; s++) { w[s] = __expf(w[s] - m); sum += w[s]; }
        float inv = 1.0f / sum;
        #pragma unroll
        for (int s = 0; s < S; s++) w[s] *= inv;
    }
    float agg_uu = 0.f;
    {
        int   ni[S];
        #pragma unroll
        for (int s = 0; s < S; s++) ni[s] = neigh_uu[(long)u * S + s];
        float r[S];
        #pragma unroll
        for (int s = 0; s < S; s++) r[s] = usr_feat[(long)ni[s] * DIM + lane];
        #pragma unroll
        for (int s = 0; s < S; s++) agg_uu = fmaf(w[s], r[s], agg_uu);
    }

    // interacted items: softmax over rat*vot*tim
    {
        float m = -INFINITY;
        #pragma unroll
        for (int s = 0; s < S; s++) {
            float sc = neigh_ui_rat[(long)u * S + s] * neigh_ui_vot[(long)u * S + s]
                     * neigh_ui_tim[(long)u * S + s];
            w[s] = sc; m = fmaxf(m, sc);
        }
        float sum = 0.f;
        #pragma unroll
        for (int s = 0; s < S; s++) { w[s] = __expf(w[s] - m); sum += w[s]; }
        float inv = 1.0f / sum;
        #pragma unroll
        for (int s = 0; s < S; s++) w[s] *= inv;
    }
    float agg_ui = 0.f;
    {
        int ni[S];
        #pragma unroll
        for (int s = 0; s < S; s++) ni[s] = neigh_ui[(long)u * S + s];
        float r[S];
        #pragma unroll
        for (int s = 0; s < S; s++) r[s] = item_feat[(long)ni[s] * DIM + lane];
        #pragma unroll
        for (int s = 0; s < S; s++) agg_ui = fmaf(w[s], r[s], agg_ui);
    }

    // user_h = relu(x @ Wu + bu)
    float xu = u_d + agg_uu + agg_ui;
    float hu = sbu[lane];
    #pragma unroll
    for (int d = 0; d < DIM; d++) {
        float xd = __shfl(xu, d);
        hu = fmaf(xd, sWu[d * DIM + lane], hu);
    }
    hu = fmaxf(hu, 0.f);

    // ---------------- item side ----------------
    // interacting users: softmax over rat*vot*tim
    {
        float m = -INFINITY;
        #pragma unroll
        for (int s = 0; s < S; s++) {
            float sc = neigh_iu_rat[(long)v * S + s] * neigh_iu_vot[(long)v * S + s]
                     * neigh_iu_tim[(long)v * S + s];
            w[s] = sc; m = fmaxf(m, sc);
        }
        float sum = 0.f;
        #pragma unroll
        for (int s = 0; s < S; s++) { w[s] = __expf(w[s] - m); sum += w[s]; }
        float inv = 1.0f / sum;
        #pragma unroll
        for (int s = 0; s < S; s++) w[s] *= inv;
    }
    float agg_iu = 0.f;
    {
        int ni[S];
        #pragma unroll
        for (int s = 0; s < S; s++) ni[s] = neigh_iu[(long)v * S + s];
        float r[S];
        #pragma unroll
        for (int s = 0; s < S; s++) r[s] = usr_feat[(long)ni[s] * DIM + lane];
        #pragma unroll
        for (int s = 0; s < S; s++) agg_iu = fmaf(w[s], r[s], agg_iu);
    }

    // KG neighbors with user-relation attention
    {
        int nr[S];
        #pragma unroll
        for (int s = 0; s < S; s++) nr[s] = neigh_ir[(long)v * S + s];
        #pragma unroll
        for (int s = 0; s < S; s++) {
            float p = u_d * rel_feat[(long)nr[s] * DIM + lane];
            #pragma unroll
            for (int off = 32; off > 0; off >>= 1) p += __shfl_xor(p, off);
            w[s] = p;
        }
        float m = -INFINITY;
        #pragma unroll
        for (int s = 0; s < S; s++) m = fmaxf(m, w[s]);
        float sum = 0.f;
        #pragma unroll
        for (int s = 0; s < S; s++) { w[s] = __expf(w[s] - m); sum += w[s]; }
        float inv = 1.0f / sum;
        #pragma unroll
        for (int s = 0; s < S; s++) w[s] *= inv;
    }
    float agg_ii = 0.f;
    {
        int ni[S];
        #pragma unroll
        for (int s = 0; s < S; s++) ni[s] = neigh_ii[(long)v * S + s];
        float r[S];
        #pragma unroll
        for (int s = 0; s < S; s++) r[s] = item_feat[(long)ni[s] * DIM + lane];
        #pragma unroll
        for (int s = 0; s < S; s++) agg_ii = fmaf(w[s], r[s], agg_ii);
    }

    // item_h = relu(x @ Wv + bv)
    float xv = v_d + agg_iu + agg_ii;
    float hv = sbv[lane];
    #pragma unroll
    for (int d = 0; d < DIM; d++) {
        float xd = __shfl(xv, d);
        hv = fmaf(xd, sWv[d * DIM + lane], hv);
    }
    hv = fmaxf(hv, 0.f);

    // score = sigmoid(dot(user_h, item_h)) * 5
    float p = hu * hv;
    #pragma unroll
    for (int off = 32; off > 0; off >>= 1) p += __shfl_xor(p, off);
    if (lane == 0) out[b] = 5.0f / (1.0f + __expf(-p));
}

extern "C" void kernel_launch(void* const* d_in, const int* in_sizes, int n_in,
                              void* d_out, int out_size, void* d_ws, size_t ws_size,
                              hipStream_t stream) {
    const int*   u_idx        = (const int*)  d_in[0];
    const int*   v_idx        = (const int*)  d_in[1];
    const float* usr_feat     = (const float*)d_in[2];
    const float* item_feat    = (const float*)d_in[3];
    const float* rel_feat     = (const float*)d_in[4];
    const int*   neigh_uu     = (const int*)  d_in[5];
    const float* neigh_uu_st  = (const float*)d_in[6];
    const int*   neigh_ui     = (const int*)  d_in[7];
    const float* neigh_ui_rat = (const float*)d_in[8];
    const float* neigh_ui_vot = (const float*)d_in[9];
    const float* neigh_ui_tim = (const float*)d_in[10];
    const int*   neigh_iu     = (const int*)  d_in[11];
    const float* neigh_iu_rat = (const float*)d_in[12];
    const float* neigh_iu_vot = (const float*)d_in[13];
    const float* neigh_iu_tim = (const float*)d_in[14];
    const int*   neigh_ii     = (const int*)  d_in[15];
    const int*   neigh_ir     = (const int*)  d_in[16];
    const float* Wu           = (const float*)d_in[17];
    const float* bu           = (const float*)d_in[18];
    const float* Wv           = (const float*)d_in[19];
    const float* bv           = (const float*)d_in[20];
    float*       out          = (float*)d_out;

    const int n = in_sizes[0];
    const int blocks = (n + WPB - 1) / WPB;
    sestkgcn_kernel<<<blocks, BLOCK, 0, stream>>>(
        u_idx, v_idx, usr_feat, item_feat, rel_feat,
        neigh_uu, neigh_uu_st, neigh_ui, neigh_ui_rat, neigh_ui_vot, neigh_ui_tim,
        neigh_iu, neigh_iu_rat, neigh_iu_vot, neigh_iu_tim, neigh_ii, neigh_ir,
        Wu, bu, Wv, bv, out, n);
}

// Round 2
// 292.237 us; speedup vs baseline: 1.1448x; 1.1448x over previous
//
#include <hip/hip_runtime.h>
#include <math.h>

constexpr int DIM = 64;
constexpr int S = 8;
constexpr int WPB = 8;                 // waves per block
constexpr int BLOCK = WPB * 64;
constexpr int WSTR = 68;               // transposed-W LDS row stride (floats); 68*4=272 B, 16B-aligned,
                                       // rotates b128 granules across bank groups -> conflict-free throughput

__global__ __launch_bounds__(BLOCK)
void sestkgcn_kernel(
    const int*   __restrict__ u_idx,
    const int*   __restrict__ v_idx,
    const float* __restrict__ usr_feat,
    const float* __restrict__ item_feat,
    const float* __restrict__ rel_feat,
    const int*   __restrict__ neigh_uu,
    const float* __restrict__ neigh_uu_st,
    const int*   __restrict__ neigh_ui,
    const float* __restrict__ neigh_ui_rat,
    const float* __restrict__ neigh_ui_vot,
    const float* __restrict__ neigh_ui_tim,
    const int*   __restrict__ neigh_iu,
    const float* __restrict__ neigh_iu_rat,
    const float* __restrict__ neigh_iu_vot,
    const float* __restrict__ neigh_iu_tim,
    const int*   __restrict__ neigh_ii,
    const int*   __restrict__ neigh_ir,
    const float* __restrict__ Wu,
    const float* __restrict__ bu,
    const float* __restrict__ Wv,
    const float* __restrict__ bv,
    float*       __restrict__ out,
    int n)
{
    // transposed weights: sWT[j*WSTR + d] = W[d*64 + j]
    __shared__ float sWuT[DIM * WSTR];
    __shared__ float sWvT[DIM * WSTR];
    __shared__ float sbu[DIM];
    __shared__ float sbv[DIM];
    __shared__ float xs[WPB * DIM];    // per-wave x spill strip

    const int tid = threadIdx.x;
    for (int i = tid; i < DIM * DIM; i += BLOCK) {
        const int d_ = i >> 6, j_ = i & 63;
        sWuT[j_ * WSTR + d_] = Wu[i];
        sWvT[j_ * WSTR + d_] = Wv[i];
    }
    if (tid < DIM) { sbu[tid] = bu[tid]; sbv[tid] = bv[tid]; }
    __syncthreads();

    const int wave = tid >> 6;
    const int lane = tid & 63;
    const int b = blockIdx.x * WPB + wave;
    if (b >= n) return;

    const int u = u_idx[b];
    const int v = v_idx[b];

    const float u_d = usr_feat[(long)u * DIM + lane];
    const float v_d = item_feat[(long)v * DIM + lane];

    float* xw = &xs[wave * DIM];
    const float4* wuT = (const float4*)&sWuT[lane * WSTR];
    const float4* wvT = (const float4*)&sWvT[lane * WSTR];
    const float4* xw4 = (const float4*)xw;

    // ---------------- user side ----------------
    float w[S];
    {   // social neighbors: softmax over tie strength
        float m = -INFINITY;
        #pragma unroll
        for (int s = 0; s < S; s++) { w[s] = neigh_uu_st[(long)u * S + s]; m = fmaxf(m, w[s]); }
        float sum = 0.f;
        #pragma unroll
        for (int s = 0; s < S; s++) { w[s] = __expf(w[s] - m); sum += w[s]; }
        float inv = 1.0f / sum;
        #pragma unroll
        for (int s = 0; s < S; s++) w[s] *= inv;
    }
    float agg_uu = 0.f;
    {
        int ni[S];
        #pragma unroll
        for (int s = 0; s < S; s++) ni[s] = neigh_uu[(long)u * S + s];
        float r[S];
        #pragma unroll
        for (int s = 0; s < S; s++) r[s] = usr_feat[(long)ni[s] * DIM + lane];
        #pragma unroll
        for (int s = 0; s < S; s++) agg_uu = fmaf(w[s], r[s], agg_uu);
    }

    {   // interacted items: softmax over rat*vot*tim
        float m = -INFINITY;
        #pragma unroll
        for (int s = 0; s < S; s++) {
            float sc = neigh_ui_rat[(long)u * S + s] * neigh_ui_vot[(long)u * S + s]
                     * neigh_ui_tim[(long)u * S + s];
            w[s] = sc; m = fmaxf(m, sc);
        }
        float sum = 0.f;
        #pragma unroll
        for (int s = 0; s < S; s++) { w[s] = __expf(w[s] - m); sum += w[s]; }
        float inv = 1.0f / sum;
        #pragma unroll
        for (int s = 0; s < S; s++) w[s] *= inv;
    }
    float agg_ui = 0.f;
    {
        int ni[S];
        #pragma unroll
        for (int s = 0; s < S; s++) ni[s] = neigh_ui[(long)u * S + s];
        float r[S];
        #pragma unroll
        for (int s = 0; s < S; s++) r[s] = item_feat[(long)ni[s] * DIM + lane];
        #pragma unroll
        for (int s = 0; s < S; s++) agg_ui = fmaf(w[s], r[s], agg_ui);
    }

    // user_h = relu(x @ Wu + bu)  via transposed-W float4 LDS reads
    float hu;
    {
        xw[lane] = u_d + agg_uu + agg_ui;
        __threadfence_block();          // order ds_write before the b128 reads
        float a0 = 0.f, a1 = 0.f, a2 = 0.f, a3 = 0.f;
        #pragma unroll
        for (int k = 0; k < DIM / 4; k++) {
            float4 xv = xw4[k];         // wave-uniform -> broadcast
            float4 wv = wuT[k];
            a0 = fmaf(xv.x, wv.x, a0);
            a1 = fmaf(xv.y, wv.y, a1);
            a2 = fmaf(xv.z, wv.z, a2);
            a3 = fmaf(xv.w, wv.w, a3);
        }
        hu = fmaxf((a0 + a1) + (a2 + a3) + sbu[lane], 0.f);
    }

    // ---------------- item side ----------------
    {   // interacting users: softmax over rat*vot*tim
        float m = -INFINITY;
        #pragma unroll
        for (int s = 0; s < S; s++) {
            float sc = neigh_iu_rat[(long)v * S + s] * neigh_iu_vot[(long)v * S + s]
                     * neigh_iu_tim[(long)v * S + s];
            w[s] = sc; m = fmaxf(m, sc);
        }
        float sum = 0.f;
        #pragma unroll
        for (int s = 0; s < S; s++) { w[s] = __expf(w[s] - m); sum += w[s]; }
        float inv = 1.0f / sum;
        #pragma unroll
        for (int s = 0; s < S; s++) w[s] *= inv;
    }
    float agg_iu = 0.f;
    {
        int ni[S];
        #pragma unroll
        for (int s = 0; s < S; s++) ni[s] = neigh_iu[(long)v * S + s];
        float r[S];
        #pragma unroll
        for (int s = 0; s < S; s++) r[s] = usr_feat[(long)ni[s] * DIM + lane];
        #pragma unroll
        for (int s = 0; s < S; s++) agg_iu = fmaf(w[s], r[s], agg_iu);
    }

    {   // KG neighbors with user-relation attention
        int nr[S];
        #pragma unroll
        for (int s = 0; s < S; s++) nr[s] = neigh_ir[(long)v * S + s];
        #pragma unroll
        for (int s = 0; s < S; s++) {
            float p = u_d * rel_feat[(long)nr[s] * DIM + lane];
            #pragma unroll
            for (int off = 32; off > 0; off >>= 1) p += __shfl_xor(p, off);
            w[s] = p;
        }
        float m = -INFINITY;
        #pragma unroll
        for (int s = 0; s < S; s++) m = fmaxf(m, w[s]);
        float sum = 0.f;
        #pragma unroll
        for (int s = 0; s < S; s++) { w[s] = __expf(w[s] - m); sum += w[s]; }
        float inv = 1.0f / sum;
        #pragma unroll
        for (int s = 0; s < S; s++) w[s] *= inv;
    }
    float agg_ii = 0.f;
    {
        int ni[S];
        #pragma unroll
        for (int s = 0; s < S; s++) ni[s] = neigh_ii[(long)v * S + s];
        float r[S];
        #pragma unroll
        for (int s = 0; s < S; s++) r[s] = item_feat[(long)ni[s] * DIM + lane];
        #pragma unroll
        for (int s = 0; s < S; s++) agg_ii = fmaf(w[s], r[s], agg_ii);
    }

    // item_h = relu(x @ Wv + bv)
    float hv;
    {
        xw[lane] = v_d + agg_iu + agg_ii;
        __threadfence_block();
        float a0 = 0.f, a1 = 0.f, a2 = 0.f, a3 = 0.f;
        #pragma unroll
        for (int k = 0; k < DIM / 4; k++) {
            float4 xv = xw4[k];
            float4 wv = wvT[k];
            a0 = fmaf(xv.x, wv.x, a0);
            a1 = fmaf(xv.y, wv.y, a1);
            a2 = fmaf(xv.z, wv.z, a2);
            a3 = fmaf(xv.w, wv.w, a3);
        }
        hv = fmaxf((a0 + a1) + (a2 + a3) + sbv[lane], 0.f);
    }

    // score = sigmoid(dot(user_h, item_h)) * 5
    float p = hu * hv;
    #pragma unroll
    for (int off = 32; off > 0; off >>= 1) p += __shfl_xor(p, off);
    if (lane == 0) out[b] = 5.0f / (1.0f + __expf(-p));
}

extern "C" void kernel_launch(void* const* d_in, const int* in_sizes, int n_in,
                              void* d_out, int out_size, void* d_ws, size_t ws_size,
                              hipStream_t stream) {
    const int*   u_idx        = (const int*)  d_in[0];
    const int*   v_idx        = (const int*)  d_in[1];
    const float* usr_feat     = (const float*)d_in[2];
    const float* item_feat    = (const float*)d_in[3];
    const float* rel_feat     = (const float*)d_in[4];
    const int*   neigh_uu     = (const int*)  d_in[5];
    const float* neigh_uu_st  = (const float*)d_in[6];
    const int*   neigh_ui     = (const int*)  d_in[7];
    const float* neigh_ui_rat = (const float*)d_in[8];
    const float* neigh_ui_vot = (const float*)d_in[9];
    const float* neigh_ui_tim = (const float*)d_in[10];
    const int*   neigh_iu     = (const int*)  d_in[11];
    const float* neigh_iu_rat = (const float*)d_in[12];
    const float* neigh_iu_vot = (const float*)d_in[13];
    const float* neigh_iu_tim = (const float*)d_in[14];
    const int*   neigh_ii     = (const int*)  d_in[15];
    const int*   neigh_ir     = (const int*)  d_in[16];
    const float* Wu           = (const float*)d_in[17];
    const float* bu           = (const float*)d_in[18];
    const float* Wv           = (const float*)d_in[19];
    const float* bv           = (const float*)d_in[20];
    float*       out          = (float*)d_out;

    const int n = in_sizes[0];
    const int blocks = (n + WPB - 1) / WPB;
    sestkgcn_kernel<<<blocks, BLOCK, 0, stream>>>(
        u_idx, v_idx, usr_feat, item_feat, rel_feat,
        neigh_uu, neigh_uu_st, neigh_ui, neigh_ui_rat, neigh_ui_vot, neigh_ui_tim,
        neigh_iu, neigh_iu_rat, neigh_iu_vot, neigh_iu_tim, neigh_ii, neigh_ir,
        Wu, bu, Wv, bv, out, n);
}

// Round 3
// 254.615 us; speedup vs baseline: 1.3139x; 1.1478x over previous
//
#include <hip/hip_runtime.h>
#include <math.h>

constexpr int DIM = 64;
constexpr int S = 8;
constexpr int WPB = 8;                 // waves per block
constexpr int BLOCK = WPB * 64;
constexpr int GRID = 1024;             // 4 blocks/CU resident -> 32 waves/CU; grid-stride over batch
constexpr int WSTR = 68;               // W^T LDS row stride: lane*68%32 = 4*lane%32 -> distinct bank-quads
                                       // per 8 lanes -> b128 reads conflict-free

// distributed 8-way softmax: sc = score for s=(lane&7), replicated across octets.
// returns w[0..7] broadcast to all lanes.
__device__ __forceinline__ void octet_softmax(float sc, float* wout) {
    float m = sc;
    m = fmaxf(m, __shfl_xor(m, 1));
    m = fmaxf(m, __shfl_xor(m, 2));
    m = fmaxf(m, __shfl_xor(m, 4));
    float e = __expf(sc - m);
    float s = e;
    s += __shfl_xor(s, 1);
    s += __shfl_xor(s, 2);
    s += __shfl_xor(s, 4);
    float w = e / s;
    #pragma unroll
    for (int k = 0; k < 8; k++) wout[k] = __shfl(w, k);   // lane k holds s=k
}

__global__ __launch_bounds__(BLOCK)
void sestkgcn_kernel(
    const int*   __restrict__ u_idx,
    const int*   __restrict__ v_idx,
    const float* __restrict__ usr_feat,
    const float* __restrict__ item_feat,
    const float* __restrict__ rel_feat,
    const int*   __restrict__ neigh_uu,
    const float* __restrict__ neigh_uu_st,
    const int*   __restrict__ neigh_ui,
    const float* __restrict__ neigh_ui_rat,
    const float* __restrict__ neigh_ui_vot,
    const float* __restrict__ neigh_ui_tim,
    const int*   __restrict__ neigh_iu,
    const float* __restrict__ neigh_iu_rat,
    const float* __restrict__ neigh_iu_vot,
    const float* __restrict__ neigh_iu_tim,
    const int*   __restrict__ neigh_ii,
    const int*   __restrict__ neigh_ir,
    const float* __restrict__ Wu,
    const float* __restrict__ bu,
    const float* __restrict__ Wv,
    const float* __restrict__ bv,
    float*       __restrict__ out,
    int n)
{
    __shared__ float sWuT[DIM * WSTR];
    __shared__ float sWvT[DIM * WSTR];
    __shared__ float sbu[DIM];
    __shared__ float sbv[DIM];
    __shared__ float xs[WPB * DIM];

    const int tid = threadIdx.x;
    for (int i = tid; i < DIM * DIM; i += BLOCK) {
        const int d_ = i >> 6, j_ = i & 63;
        sWuT[j_ * WSTR + d_] = Wu[i];
        sWvT[j_ * WSTR + d_] = Wv[i];
    }
    if (tid < DIM) { sbu[tid] = bu[tid]; sbv[tid] = bv[tid]; }
    __syncthreads();

    const int wave = tid >> 6;
    const int lane = tid & 63;
    const int ls   = lane & 7;

    float* xw = &xs[wave * DIM];
    const float4* wuT = (const float4*)&sWuT[lane * WSTR];
    const float4* wvT = (const float4*)&sWvT[lane * WSTR];
    const float4* xw4 = (const float4*)xw;
    const float bu_l = sbu[lane];
    const float bv_l = sbv[lane];

    const int stride = GRID * WPB;
    for (int b = blockIdx.x * WPB + wave; b < n; b += stride) {
        const int u = u_idx[b];
        const int v = v_idx[b];
        const unsigned u8 = (unsigned)u << 3, v8 = (unsigned)v << 3;
        const unsigned u64o = (unsigned)u << 6, v64o = (unsigned)v << 6;

        const float u_d = usr_feat[u64o | (unsigned)lane];
        const float v_d = item_feat[v64o | (unsigned)lane];

        // per-lane scores (s = lane&7), coalesced 32B per octet-group
        const float sc_uu = neigh_uu_st[u8 + ls];
        const float sc_ui = neigh_ui_rat[u8 + ls] * neigh_ui_vot[u8 + ls] * neigh_ui_tim[u8 + ls];
        const float sc_iu = neigh_iu_rat[v8 + ls] * neigh_iu_vot[v8 + ls] * neigh_iu_tim[v8 + ls];

        // ---------------- user side ----------------
        float w[S];
        octet_softmax(sc_uu, w);
        float agg_uu = 0.f;
        {
            const int4 i0 = ((const int4*)(neigh_uu + u8))[0];
            const int4 i1 = ((const int4*)(neigh_uu + u8))[1];
            const int ni[S] = {i0.x, i0.y, i0.z, i0.w, i1.x, i1.y, i1.z, i1.w};
            float r[S];
            #pragma unroll
            for (int s = 0; s < S; s++) r[s] = usr_feat[((unsigned)ni[s] << 6) | (unsigned)lane];
            #pragma unroll
            for (int s = 0; s < S; s++) agg_uu = fmaf(w[s], r[s], agg_uu);
        }

        octet_softmax(sc_ui, w);
        float agg_ui = 0.f;
        {
            const int4 i0 = ((const int4*)(neigh_ui + u8))[0];
            const int4 i1 = ((const int4*)(neigh_ui + u8))[1];
            const int ni[S] = {i0.x, i0.y, i0.z, i0.w, i1.x, i1.y, i1.z, i1.w};
            float r[S];
            #pragma unroll
            for (int s = 0; s < S; s++) r[s] = item_feat[((unsigned)ni[s] << 6) | (unsigned)lane];
            #pragma unroll
            for (int s = 0; s < S; s++) agg_ui = fmaf(w[s], r[s], agg_ui);
        }

        // user_h = relu(x @ Wu + bu)
        float hu;
        {
            xw[lane] = u_d + agg_uu + agg_ui;
            __threadfence_block();
            float a0 = 0.f, a1 = 0.f, a2 = 0.f, a3 = 0.f;
            #pragma unroll
            for (int k = 0; k < DIM / 4; k++) {
                float4 xv = xw4[k];
                float4 wv = wuT[k];
                a0 = fmaf(xv.x, wv.x, a0);
                a1 = fmaf(xv.y, wv.y, a1);
                a2 = fmaf(xv.z, wv.z, a2);
                a3 = fmaf(xv.w, wv.w, a3);
            }
            hu = fmaxf((a0 + a1) + (a2 + a3) + bu_l, 0.f);
        }

        // ---------------- item side ----------------
        octet_softmax(sc_iu, w);
        float agg_iu = 0.f;
        {
            const int4 i0 = ((const int4*)(neigh_iu + v8))[0];
            const int4 i1 = ((const int4*)(neigh_iu + v8))[1];
            const int ni[S] = {i0.x, i0.y, i0.z, i0.w, i1.x, i1.y, i1.z, i1.w};
            float r[S];
            #pragma unroll
            for (int s = 0; s < S; s++) r[s] = usr_feat[((unsigned)ni[s] << 6) | (unsigned)lane];
            #pragma unroll
            for (int s = 0; s < S; s++) agg_iu = fmaf(w[s], r[s], agg_iu);
        }

        // KG attention: p[s] = dot(u_emb, rel[s]); merge 8 wave-reductions so
        // lane ends holding the total for s=lane&7, then octet softmax.
        {
            const int4 r0 = ((const int4*)(neigh_ir + v8))[0];
            const int4 r1 = ((const int4*)(neigh_ir + v8))[1];
            const int nr[S] = {r0.x, r0.y, r0.z, r0.w, r1.x, r1.y, r1.z, r1.w};
            float p[S];
            #pragma unroll
            for (int s = 0; s < S; s++) p[s] = u_d * rel_feat[((unsigned)nr[s] << 6) | (unsigned)lane];

            float m1[4];
            #pragma unroll
            for (int i = 0; i < 4; i++) {
                float lo = (lane & 1) ? p[2 * i + 1] : p[2 * i];
                float hi = (lane & 1) ? p[2 * i]     : p[2 * i + 1];
                m1[i] = lo + __shfl_xor(hi, 1);
            }
            float m2[2];
            #pragma unroll
            for (int i = 0; i < 2; i++) {
                float lo = (lane & 2) ? m1[2 * i + 1] : m1[2 * i];
                float hi = (lane & 2) ? m1[2 * i]     : m1[2 * i + 1];
                m2[i] = lo + __shfl_xor(hi, 2);
            }
            float lo = (lane & 4) ? m2[1] : m2[0];
            float hi = (lane & 4) ? m2[0] : m2[1];
            float att = lo + __shfl_xor(hi, 4);
            att += __shfl_xor(att, 8);
            att += __shfl_xor(att, 16);
            att += __shfl_xor(att, 32);
            octet_softmax(att, w);
        }
        float agg_ii = 0.f;
        {
            const int4 i0 = ((const int4*)(neigh_ii + v8))[0];
            const int4 i1 = ((const int4*)(neigh_ii + v8))[1];
            const int ni[S] = {i0.x, i0.y, i0.z, i0.w, i1.x, i1.y, i1.z, i1.w};
            float r[S];
            #pragma unroll
            for (int s = 0; s < S; s++) r[s] = item_feat[((unsigned)ni[s] << 6) | (unsigned)lane];
            #pragma unroll
            for (int s = 0; s < S; s++) agg_ii = fmaf(w[s], r[s], agg_ii);
        }

        // item_h = relu(x @ Wv + bv)
        float hv;
        {
            xw[lane] = v_d + agg_iu + agg_ii;
            __threadfence_block();
            float a0 = 0.f, a1 = 0.f, a2 = 0.f, a3 = 0.f;
            #pragma unroll
            for (int k = 0; k < DIM / 4; k++) {
                float4 xv = xw4[k];
                float4 wv = wvT[k];
                a0 = fmaf(xv.x, wv.x, a0);
                a1 = fmaf(xv.y, wv.y, a1);
                a2 = fmaf(xv.z, wv.z, a2);
                a3 = fmaf(xv.w, wv.w, a3);
            }
            hv = fmaxf((a0 + a1) + (a2 + a3) + bv_l, 0.f);
        }

        // score = sigmoid(dot(user_h, item_h)) * 5
        float p = hu * hv;
        #pragma unroll
        for (int off = 32; off > 0; off >>= 1) p += __shfl_xor(p, off);
        if (lane == 0) out[b] = 5.0f / (1.0f + __expf(-p));
    }
}

extern "C" void kernel_launch(void* const* d_in, const int* in_sizes, int n_in,
                              void* d_out, int out_size, void* d_ws, size_t ws_size,
                              hipStream_t stream) {
    const int*   u_idx        = (const int*)  d_in[0];
    const int*   v_idx        = (const int*)  d_in[1];
    const float* usr_feat     = (const float*)d_in[2];
    const float* item_feat    = (const float*)d_in[3];
    const float* rel_feat     = (const float*)d_in[4];
    const int*   neigh_uu     = (const int*)  d_in[5];
    const float* neigh_uu_st  = (const float*)d_in[6];
    const int*   neigh_ui     = (const int*)  d_in[7];
    const float* neigh_ui_rat = (const float*)d_in[8];
    const float* neigh_ui_vot = (const float*)d_in[9];
    const float* neigh_ui_tim = (const float*)d_in[10];
    const int*   neigh_iu     = (const int*)  d_in[11];
    const float* neigh_iu_rat = (const float*)d_in[12];
    const float* neigh_iu_vot = (const float*)d_in[13];
    const float* neigh_iu_tim = (const float*)d_in[14];
    const int*   neigh_ii     = (const int*)  d_in[15];
    const int*   neigh_ir     = (const int*)  d_in[16];
    const float* Wu           = (const float*)d_in[17];
    const float* bu           = (const float*)d_in[18];
    const float* Wv           = (const float*)d_in[19];
    const float* bv           = (const float*)d_in[20];
    float*       out          = (float*)d_out;

    const int n = in_sizes[0];
    int blocks = (n + WPB - 1) / WPB;
    if (blocks > GRID) blocks = GRID;
    sestkgcn_kernel<<<blocks, BLOCK, 0, stream>>>(
        u_idx, v_idx, usr_feat, item_feat, rel_feat,
        neigh_uu, neigh_uu_st, neigh_ui, neigh_ui_rat, neigh_ui_vot, neigh_ui_tim,
        neigh_iu, neigh_iu_rat, neigh_iu_vot, neigh_iu_tim, neigh_ii, neigh_ir,
        Wu, bu, Wv, bv, out, n);
}